// Round 3
// baseline (595.981 us; speedup 1.0000x reference)
//
#include <hip/hip_runtime.h>
#include <math.h>

// Round 3: spatial counting-sort (32^3 bins) + fused encode/MLP over sorted
// points. Round 2 was gather-transaction-bound (VALUBusy 25%, HBM 1.7%,
// nothing saturated): random points -> 64 distinct cache lines per wave
// gather. Sorting makes waves spatially coherent -> gathers become ~2-4
// lines (broadcast-ish), collapsing the L1 transaction count.
//
// Pipeline (all on `stream`, deterministic output):
//   memset hist -> hist_kernel (atomicAdd) -> scan_kernel (1 block)
//   -> scatter_kernel (pos = atomicAdd(offs), xs[pos] = {x,y,z,idx})
//   -> main_kernel (sorted coalesced read, scatter write out[idx])
// Atomic order only permutes which thread computes a point, not its value.
// Falls back to the round-2 fused kernel if ws_size is too small.

typedef float v2f __attribute__((ext_vector_type(2)));

struct EncParams {
    float scale[8];
};

#define NBINS 32768  // 32^3 spatial bins

__device__ __forceinline__ int bin_of(float px, float py, float pz) {
    int bx = min(31, max(0, (int)(px * 32.0f)));
    int by = min(31, max(0, (int)(py * 32.0f)));
    int bz = min(31, max(0, (int)(pz * 32.0f)));
    return (bz * 32 + by) * 32 + bx;
}

__global__ __launch_bounds__(256) void hist_kernel(
    const float* __restrict__ x, int N, int* __restrict__ hist)
{
    const int gid = blockIdx.x * 256 + threadIdx.x;
    if (gid >= N) return;
    const float px = x[3 * gid + 0];
    const float py = x[3 * gid + 1];
    const float pz = x[3 * gid + 2];
    atomicAdd(&hist[bin_of(px, py, pz)], 1);
}

__global__ __launch_bounds__(1024) void scan_kernel(
    const int* __restrict__ hist, int* __restrict__ offs)
{
    __shared__ int s[1024];
    const int t = threadIdx.x;
    int local[32];
    int sum = 0;
    #pragma unroll
    for (int k = 0; k < 32; ++k) { local[k] = hist[t * 32 + k]; sum += local[k]; }
    s[t] = sum;
    __syncthreads();
    // Hillis-Steele inclusive scan over 1024 partial sums
    for (int off = 1; off < 1024; off <<= 1) {
        const int v = (t >= off) ? s[t - off] : 0;
        __syncthreads();
        s[t] += v;
        __syncthreads();
    }
    int excl = s[t] - sum;
    #pragma unroll
    for (int k = 0; k < 32; ++k) { offs[t * 32 + k] = excl; excl += local[k]; }
}

__global__ __launch_bounds__(256) void scatter_kernel(
    const float* __restrict__ x, int N, int* __restrict__ offs,
    float4* __restrict__ xs)
{
    const int gid = blockIdx.x * 256 + threadIdx.x;
    if (gid >= N) return;
    const float px = x[3 * gid + 0];
    const float py = x[3 * gid + 1];
    const float pz = x[3 * gid + 2];
    const int b = bin_of(px, py, pz);
    const int pos = atomicAdd(&offs[b], 1);
    xs[pos] = make_float4(px, py, pz, __int_as_float(gid));
}

__global__ __launch_bounds__(256) void sdf_main_kernel(
    const float4* __restrict__ xs,
    const float* __restrict__ table,
    const float* __restrict__ W0,
    const float* __restrict__ W1,
    const float* __restrict__ W2,
    float* __restrict__ out,
    int N, EncParams ep)
{
    constexpr int SIDE[8] = {9, 11, 13, 16, 19, 23, 28, 33};
    constexpr int OFF[8]  = {0, 729, 2060, 4257, 8353, 15212, 27379, 49331};

    __shared__ __align__(16) float sW0t[256];   // transposed [i][j]
    __shared__ __align__(16) float sW1t[256];
    __shared__ __align__(16) float sW2[16];

    const int t = threadIdx.x;
    sW0t[(t & 15) * 16 + (t >> 4)] = W0[t];
    sW1t[(t & 15) * 16 + (t >> 4)] = W1[t];
    if (t < 16) sW2[t] = W2[t];
    __syncthreads();

    const int gid = blockIdx.x * 256 + t;
    if (gid >= N) return;

    const float4 p = xs[gid];
    const float px = p.x, py = p.y, pz = p.z;
    const int oidx = __float_as_int(p.w);

    v2f hl[8];

    #pragma unroll
    for (int l = 0; l < 8; ++l) {
        const int side  = SIDE[l];
        const int side2 = side * side;
        const float s = ep.scale[l];
        const float fx = px * s + 0.5f;
        const float fy = py * s + 0.5f;
        const float fz = pz * s + 0.5f;
        const float gx = floorf(fx), gy = floorf(fy), gz = floorf(fz);
        const float rx = fx - gx, ry = fy - gy, rz = fz - gz;
        const int ix = (int)gx, iy = (int)gy, iz = (int)gz;
        const int base = OFF[l] + ix + iy * side + iz * side2;

        const float wx0 = 1.0f - rx;
        const float wy0 = 1.0f - ry;
        const float wz0 = 1.0f - rz;

        v2f acc = {0.0f, 0.0f};
        #pragma unroll
        for (int dz = 0; dz < 2; ++dz) {
            const float wz = dz ? rz : wz0;
            #pragma unroll
            for (int dy = 0; dy < 2; ++dy) {
                const float wyz = (dy ? ry : wy0) * wz;
                const int r = base + dy * side + dz * side2;
                // corner-pair rows (r, r+1) = 4 consecutive floats, 8B aligned
                const float4 f = *reinterpret_cast<const float4*>(table + 2 * r);
                const v2f v0 = {f.x, f.y};
                const v2f v1 = {f.z, f.w};
                acc += (wyz * wx0) * v0 + (wyz * rx) * v1;
            }
        }
        hl[l] = acc;
    }

    // ---- MLP, packed fp32 ----
    v2f a[8];
    #pragma unroll
    for (int j = 0; j < 8; ++j) a[j] = (v2f){0.0f, 0.0f};
    #pragma unroll
    for (int i2 = 0; i2 < 8; ++i2) {
        const float h0 = hl[i2].x;
        const float h1 = hl[i2].y;
        const float4* w0 = reinterpret_cast<const float4*>(&sW0t[(2 * i2) * 16]);
        const float4* w1 = reinterpret_cast<const float4*>(&sW0t[(2 * i2 + 1) * 16]);
        #pragma unroll
        for (int q = 0; q < 4; ++q) {
            const float4 wa = w0[q];
            const float4 wb = w1[q];
            a[2 * q]     += h0 * (v2f){wa.x, wa.y};
            a[2 * q + 1] += h0 * (v2f){wa.z, wa.w};
            a[2 * q]     += h1 * (v2f){wb.x, wb.y};
            a[2 * q + 1] += h1 * (v2f){wb.z, wb.w};
        }
    }
    const v2f zz = {0.0f, 0.0f};
    v2f h1v[8];
    #pragma unroll
    for (int j = 0; j < 8; ++j) h1v[j] = __builtin_elementwise_max(a[j], zz);

    #pragma unroll
    for (int j = 0; j < 8; ++j) a[j] = (v2f){0.0f, 0.0f};
    #pragma unroll
    for (int i2 = 0; i2 < 8; ++i2) {
        const float h0 = h1v[i2].x;
        const float h1 = h1v[i2].y;
        const float4* w0 = reinterpret_cast<const float4*>(&sW1t[(2 * i2) * 16]);
        const float4* w1 = reinterpret_cast<const float4*>(&sW1t[(2 * i2 + 1) * 16]);
        #pragma unroll
        for (int q = 0; q < 4; ++q) {
            const float4 wa = w0[q];
            const float4 wb = w1[q];
            a[2 * q]     += h0 * (v2f){wa.x, wa.y};
            a[2 * q + 1] += h0 * (v2f){wa.z, wa.w};
            a[2 * q]     += h1 * (v2f){wb.x, wb.y};
            a[2 * q + 1] += h1 * (v2f){wb.z, wb.w};
        }
    }

    v2f acco = {0.0f, 0.0f};
    #pragma unroll
    for (int j = 0; j < 8; ++j) {
        const v2f h2 = __builtin_elementwise_max(a[j], zz);
        const v2f w2 = {sW2[2 * j], sW2[2 * j + 1]};
        acco += h2 * w2;
    }
    out[oidx] = acco.x + acco.y;
}

// ---- fallback (round-2 kernel) if ws is too small for the sort path ----
__global__ __launch_bounds__(512) void sdf_fused_fallback(
    const float* __restrict__ x,
    const float* __restrict__ table,
    const float* __restrict__ W0,
    const float* __restrict__ W1,
    const float* __restrict__ W2,
    float* __restrict__ out,
    int N, EncParams ep)
{
    constexpr int SIDE[8] = {9, 11, 13, 16, 19, 23, 28, 33};
    constexpr int OFF[8]  = {0, 729, 2060, 4257, 8353, 15212, 27379, 49331};
    constexpr int NROWS_LDS = 4257;

    __shared__ __align__(16) float sTab[2 * NROWS_LDS];
    __shared__ __align__(16) float sW0t[256];
    __shared__ __align__(16) float sW1t[256];
    __shared__ __align__(16) float sW2[16];

    const int t = threadIdx.x;
    if (t < 256) {
        sW0t[(t & 15) * 16 + (t >> 4)] = W0[t];
        sW1t[(t & 15) * 16 + (t >> 4)] = W1[t];
        if (t < 16) sW2[t] = W2[t];
    }
    {
        const float2* tb2 = reinterpret_cast<const float2*>(table);
        float2* sT2 = reinterpret_cast<float2*>(sTab);
        for (int i = t; i < NROWS_LDS; i += 512) sT2[i] = tb2[i];
    }
    __syncthreads();

    const int gid = blockIdx.x * 512 + t;
    if (gid >= N) return;

    const float px = x[3 * gid + 0];
    const float py = x[3 * gid + 1];
    const float pz = x[3 * gid + 2];

    v2f hl[8];
    const float2* sT2 = reinterpret_cast<const float2*>(sTab);

    #pragma unroll
    for (int l = 0; l < 8; ++l) {
        const int side  = SIDE[l];
        const int side2 = side * side;
        const float s = ep.scale[l];
        const float fx = px * s + 0.5f;
        const float fy = py * s + 0.5f;
        const float fz = pz * s + 0.5f;
        const float gx = floorf(fx), gy = floorf(fy), gz = floorf(fz);
        const float rx = fx - gx, ry = fy - gy, rz = fz - gz;
        const int ix = (int)gx, iy = (int)gy, iz = (int)gz;
        const int base = OFF[l] + ix + iy * side + iz * side2;
        const float wx0 = 1.0f - rx, wy0 = 1.0f - ry, wz0 = 1.0f - rz;

        v2f acc = {0.0f, 0.0f};
        if (l < 3) {
            #pragma unroll
            for (int dz = 0; dz < 2; ++dz) {
                const float wz = dz ? rz : wz0;
                #pragma unroll
                for (int dy = 0; dy < 2; ++dy) {
                    const float wyz = (dy ? ry : wy0) * wz;
                    const int r = base + dy * side + dz * side2;
                    const float2 f0 = sT2[r];
                    const float2 f1 = sT2[r + 1];
                    acc += (wyz * wx0) * (v2f){f0.x, f0.y}
                         + (wyz * rx)  * (v2f){f1.x, f1.y};
                }
            }
        } else {
            #pragma unroll
            for (int dz = 0; dz < 2; ++dz) {
                const float wz = dz ? rz : wz0;
                #pragma unroll
                for (int dy = 0; dy < 2; ++dy) {
                    const float wyz = (dy ? ry : wy0) * wz;
                    const int r = base + dy * side + dz * side2;
                    const float4 f = *reinterpret_cast<const float4*>(table + 2 * r);
                    acc += (wyz * wx0) * (v2f){f.x, f.y}
                         + (wyz * rx)  * (v2f){f.z, f.w};
                }
            }
        }
        hl[l] = acc;
    }

    v2f a[8];
    #pragma unroll
    for (int j = 0; j < 8; ++j) a[j] = (v2f){0.0f, 0.0f};
    #pragma unroll
    for (int i2 = 0; i2 < 8; ++i2) {
        const float h0 = hl[i2].x;
        const float h1 = hl[i2].y;
        const float4* w0 = reinterpret_cast<const float4*>(&sW0t[(2 * i2) * 16]);
        const float4* w1 = reinterpret_cast<const float4*>(&sW0t[(2 * i2 + 1) * 16]);
        #pragma unroll
        for (int q = 0; q < 4; ++q) {
            const float4 wa = w0[q];
            const float4 wb = w1[q];
            a[2 * q]     += h0 * (v2f){wa.x, wa.y};
            a[2 * q + 1] += h0 * (v2f){wa.z, wa.w};
            a[2 * q]     += h1 * (v2f){wb.x, wb.y};
            a[2 * q + 1] += h1 * (v2f){wb.z, wb.w};
        }
    }
    const v2f zz = {0.0f, 0.0f};
    v2f h1v[8];
    #pragma unroll
    for (int j = 0; j < 8; ++j) h1v[j] = __builtin_elementwise_max(a[j], zz);

    #pragma unroll
    for (int j = 0; j < 8; ++j) a[j] = (v2f){0.0f, 0.0f};
    #pragma unroll
    for (int i2 = 0; i2 < 8; ++i2) {
        const float h0 = h1v[i2].x;
        const float h1 = h1v[i2].y;
        const float4* w0 = reinterpret_cast<const float4*>(&sW1t[(2 * i2) * 16]);
        const float4* w1 = reinterpret_cast<const float4*>(&sW1t[(2 * i2 + 1) * 16]);
        #pragma unroll
        for (int q = 0; q < 4; ++q) {
            const float4 wa = w0[q];
            const float4 wb = w1[q];
            a[2 * q]     += h0 * (v2f){wa.x, wa.y};
            a[2 * q + 1] += h0 * (v2f){wa.z, wa.w};
            a[2 * q]     += h1 * (v2f){wb.x, wb.y};
            a[2 * q + 1] += h1 * (v2f){wb.z, wb.w};
        }
    }

    v2f acco = {0.0f, 0.0f};
    #pragma unroll
    for (int j = 0; j < 8; ++j) {
        const v2f h2 = __builtin_elementwise_max(a[j], zz);
        acco += h2 * (v2f){sW2[2 * j], sW2[2 * j + 1]};
    }
    out[gid] = acco.x + acco.y;
}

extern "C" void kernel_launch(void* const* d_in, const int* in_sizes, int n_in,
                              void* d_out, int out_size, void* d_ws, size_t ws_size,
                              hipStream_t stream) {
    const float* x     = (const float*)d_in[0];
    const float* table = (const float*)d_in[1];
    const float* W0    = (const float*)d_in[2];
    const float* W1    = (const float*)d_in[3];
    const float* W2    = (const float*)d_in[4];
    float* out = (float*)d_out;

    const int N = in_sizes[0] / 3;

    EncParams ep;
    const double g = pow(4.0, 1.0 / 7.0);
    for (int l = 0; l < 8; ++l) {
        ep.scale[l] = (float)(8.0 * pow(g, (double)l) - 1.0);
    }

    const size_t histBytes = (size_t)NBINS * 4;
    const size_t xsOff     = 2 * histBytes;                 // hist + offs
    const size_t needBytes = xsOff + (size_t)N * 16;

    if (ws_size >= needBytes) {
        int*    hist = (int*)d_ws;
        int*    offs = (int*)((char*)d_ws + histBytes);
        float4* xs   = (float4*)((char*)d_ws + xsOff);

        hipMemsetAsync(hist, 0, histBytes, stream);
        const int blocks = (N + 255) / 256;
        hipLaunchKernelGGL(hist_kernel, dim3(blocks), dim3(256), 0, stream,
                           x, N, hist);
        hipLaunchKernelGGL(scan_kernel, dim3(1), dim3(1024), 0, stream,
                           hist, offs);
        hipLaunchKernelGGL(scatter_kernel, dim3(blocks), dim3(256), 0, stream,
                           x, N, offs, xs);
        hipLaunchKernelGGL(sdf_main_kernel, dim3(blocks), dim3(256), 0, stream,
                           xs, table, W0, W1, W2, out, N, ep);
    } else {
        const int blocks = (N + 511) / 512;
        hipLaunchKernelGGL(sdf_fused_fallback, dim3(blocks), dim3(512), 0, stream,
                           x, table, W0, W1, W2, out, N, ep);
    }
}

// Round 4
// 300.581 us; speedup vs baseline: 1.9828x; 1.9828x over previous
//
#include <hip/hip_runtime.h>
#include <math.h>

// Round 4: table re-layout instead of point sort.
// Round 3 post-mortem: scatter wrote 268MB HBM (64B line per random 16B
// store) + 4.2M contended atomics -> 330us alone. Sorting moves the
// random-access cost, it doesn't remove it.
// Fix the DATA layout: build a per-cell corner block array in ws -- for each
// grid cell, all 8 corners x 2 feats = 64B, 64B-aligned = ONE cache line per
// (point, level) instead of ~4.5 lines. 75546 cells x 64B = 4.8MB, L2-resident.
// Misses/point: ~36 -> ~8. No sort, no atomics, no scatter.

typedef float v2f __attribute__((ext_vector_type(2)));

struct EncParams {
    float scale[8];
};

// grid sides (rows per axis), cell-grid sides (side-1), and offsets
__constant__ constexpr int SIDE[8] = {9, 11, 13, 16, 19, 23, 28, 33};
__constant__ constexpr int ROWOFF[8] = {0, 729, 2060, 4257, 8353, 15212, 27379, 49331};
__constant__ constexpr int CS[8]   = {8, 10, 12, 15, 18, 22, 27, 32};
__constant__ constexpr int CB[8]   = {0, 512, 1512, 3240, 6615, 12447, 23095, 42778};
#define TOTCELLS 75546   // CB[7] + 32^3

// ---- kernel 1: build per-cell 64B corner blocks from the row-major table ----
// cell c at level l, coords (ix,iy,iz) in [0,CS[l])^3:
//   quadrant q = dz*2+dy (float4): { f(dx=0).x, f(dx=0).y, f(dx=1).x, f(dx=1).y }
__global__ __launch_bounds__(256) void build_cells(
    const float* __restrict__ table, float4* __restrict__ cells)
{
    const int c = blockIdx.x * 256 + threadIdx.x;
    if (c >= TOTCELLS) return;

    int l = 0;
    #pragma unroll
    for (int i = 1; i < 8; ++i) if (c >= CB[i]) l = i;

    const int cs = CS[l];
    const int rem = c - CB[l];
    const int ix = rem % cs;
    const int t1 = rem / cs;
    const int iy = t1 % cs;
    const int iz = t1 / cs;

    const int side  = SIDE[l];
    const int side2 = side * side;
    const int row   = ROWOFF[l] + ix + iy * side + iz * side2;

    const float2* tb2 = reinterpret_cast<const float2*>(table);
    float4* dst = cells + 4 * c;

    #pragma unroll
    for (int dz = 0; dz < 2; ++dz) {
        #pragma unroll
        for (int dy = 0; dy < 2; ++dy) {
            const int r = row + dy * side + dz * side2;
            const float2 f0 = tb2[r];
            const float2 f1 = tb2[r + 1];
            dst[dz * 2 + dy] = make_float4(f0.x, f0.y, f1.x, f1.y);
        }
    }
}

// ---- kernel 2: fused encode + MLP over the cell array ----
__global__ __launch_bounds__(256) void sdf_cell_kernel(
    const float* __restrict__ x,
    const float4* __restrict__ cells,
    const float* __restrict__ W0,
    const float* __restrict__ W1,
    const float* __restrict__ W2,
    float* __restrict__ out,
    int N, EncParams ep)
{
    __shared__ __align__(16) float sW0t[256];   // transposed [i][j]
    __shared__ __align__(16) float sW1t[256];
    __shared__ __align__(16) float sW2[16];

    const int t = threadIdx.x;
    sW0t[(t & 15) * 16 + (t >> 4)] = W0[t];
    sW1t[(t & 15) * 16 + (t >> 4)] = W1[t];
    if (t < 16) sW2[t] = W2[t];
    __syncthreads();

    const int gid = blockIdx.x * 256 + t;
    if (gid >= N) return;

    const float px = x[3 * gid + 0];
    const float py = x[3 * gid + 1];
    const float pz = x[3 * gid + 2];

    v2f hl[8];

    #pragma unroll
    for (int l = 0; l < 8; ++l) {
        const int cs = CS[l];
        const float s = ep.scale[l];
        const float fx = px * s + 0.5f;
        const float fy = py * s + 0.5f;
        const float fz = pz * s + 0.5f;
        const float gx = floorf(fx), gy = floorf(fy), gz = floorf(fz);
        const float rx = fx - gx, ry = fy - gy, rz = fz - gz;
        const int ix = (int)gx, iy = (int)gy, iz = (int)gz;

        const int cell = CB[l] + (iz * cs + iy) * cs + ix;
        const float4* cq = cells + 4 * cell;   // one 64B line
        const float4 q0 = cq[0];   // dz=0,dy=0: {x0.f0,x0.f1,x1.f0,x1.f1}
        const float4 q1 = cq[1];   // dz=0,dy=1
        const float4 q2 = cq[2];   // dz=1,dy=0
        const float4 q3 = cq[3];   // dz=1,dy=1

        const float wx0 = 1.0f - rx;
        const float wy0 = 1.0f - ry;
        const float wz0 = 1.0f - rz;

        v2f acc = {0.0f, 0.0f};
        {
            const float wyz = wy0 * wz0;
            acc += (wyz * wx0) * (v2f){q0.x, q0.y} + (wyz * rx) * (v2f){q0.z, q0.w};
        }
        {
            const float wyz = ry * wz0;
            acc += (wyz * wx0) * (v2f){q1.x, q1.y} + (wyz * rx) * (v2f){q1.z, q1.w};
        }
        {
            const float wyz = wy0 * rz;
            acc += (wyz * wx0) * (v2f){q2.x, q2.y} + (wyz * rx) * (v2f){q2.z, q2.w};
        }
        {
            const float wyz = ry * rz;
            acc += (wyz * wx0) * (v2f){q3.x, q3.y} + (wyz * rx) * (v2f){q3.z, q3.w};
        }
        hl[l] = acc;
    }

    // ---- MLP, packed fp32 ----
    v2f a[8];
    #pragma unroll
    for (int j = 0; j < 8; ++j) a[j] = (v2f){0.0f, 0.0f};
    #pragma unroll
    for (int i2 = 0; i2 < 8; ++i2) {
        const float h0 = hl[i2].x;
        const float h1 = hl[i2].y;
        const float4* w0 = reinterpret_cast<const float4*>(&sW0t[(2 * i2) * 16]);
        const float4* w1 = reinterpret_cast<const float4*>(&sW0t[(2 * i2 + 1) * 16]);
        #pragma unroll
        for (int q = 0; q < 4; ++q) {
            const float4 wa = w0[q];
            const float4 wb = w1[q];
            a[2 * q]     += h0 * (v2f){wa.x, wa.y};
            a[2 * q + 1] += h0 * (v2f){wa.z, wa.w};
            a[2 * q]     += h1 * (v2f){wb.x, wb.y};
            a[2 * q + 1] += h1 * (v2f){wb.z, wb.w};
        }
    }
    const v2f zz = {0.0f, 0.0f};
    v2f h1v[8];
    #pragma unroll
    for (int j = 0; j < 8; ++j) h1v[j] = __builtin_elementwise_max(a[j], zz);

    #pragma unroll
    for (int j = 0; j < 8; ++j) a[j] = (v2f){0.0f, 0.0f};
    #pragma unroll
    for (int i2 = 0; i2 < 8; ++i2) {
        const float h0 = h1v[i2].x;
        const float h1 = h1v[i2].y;
        const float4* w0 = reinterpret_cast<const float4*>(&sW1t[(2 * i2) * 16]);
        const float4* w1 = reinterpret_cast<const float4*>(&sW1t[(2 * i2 + 1) * 16]);
        #pragma unroll
        for (int q = 0; q < 4; ++q) {
            const float4 wa = w0[q];
            const float4 wb = w1[q];
            a[2 * q]     += h0 * (v2f){wa.x, wa.y};
            a[2 * q + 1] += h0 * (v2f){wa.z, wa.w};
            a[2 * q]     += h1 * (v2f){wb.x, wb.y};
            a[2 * q + 1] += h1 * (v2f){wb.z, wb.w};
        }
    }

    v2f acco = {0.0f, 0.0f};
    #pragma unroll
    for (int j = 0; j < 8; ++j) {
        const v2f h2 = __builtin_elementwise_max(a[j], zz);
        acco += h2 * (v2f){sW2[2 * j], sW2[2 * j + 1]};
    }
    out[gid] = acco.x + acco.y;
}

// ---- fallback: direct row-major gather (round-1 style), if ws too small ----
__global__ __launch_bounds__(256) void sdf_fused_fallback(
    const float* __restrict__ x,
    const float* __restrict__ table,
    const float* __restrict__ W0,
    const float* __restrict__ W1,
    const float* __restrict__ W2,
    float* __restrict__ out,
    int N, EncParams ep)
{
    __shared__ __align__(16) float sW0t[256];
    __shared__ __align__(16) float sW1t[256];
    __shared__ __align__(16) float sW2[16];

    const int t = threadIdx.x;
    sW0t[(t & 15) * 16 + (t >> 4)] = W0[t];
    sW1t[(t & 15) * 16 + (t >> 4)] = W1[t];
    if (t < 16) sW2[t] = W2[t];
    __syncthreads();

    const int gid = blockIdx.x * 256 + t;
    if (gid >= N) return;

    const float px = x[3 * gid + 0];
    const float py = x[3 * gid + 1];
    const float pz = x[3 * gid + 2];

    v2f hl[8];

    #pragma unroll
    for (int l = 0; l < 8; ++l) {
        const int side  = SIDE[l];
        const int side2 = side * side;
        const float s = ep.scale[l];
        const float fx = px * s + 0.5f;
        const float fy = py * s + 0.5f;
        const float fz = pz * s + 0.5f;
        const float gx = floorf(fx), gy = floorf(fy), gz = floorf(fz);
        const float rx = fx - gx, ry = fy - gy, rz = fz - gz;
        const int ix = (int)gx, iy = (int)gy, iz = (int)gz;
        const int base = ROWOFF[l] + ix + iy * side + iz * side2;
        const float wx0 = 1.0f - rx, wy0 = 1.0f - ry, wz0 = 1.0f - rz;

        v2f acc = {0.0f, 0.0f};
        #pragma unroll
        for (int dz = 0; dz < 2; ++dz) {
            const float wz = dz ? rz : wz0;
            #pragma unroll
            for (int dy = 0; dy < 2; ++dy) {
                const float wyz = (dy ? ry : wy0) * wz;
                const int r = base + dy * side + dz * side2;
                const float4 f = *reinterpret_cast<const float4*>(table + 2 * r);
                acc += (wyz * wx0) * (v2f){f.x, f.y}
                     + (wyz * rx)  * (v2f){f.z, f.w};
            }
        }
        hl[l] = acc;
    }

    v2f a[8];
    #pragma unroll
    for (int j = 0; j < 8; ++j) a[j] = (v2f){0.0f, 0.0f};
    #pragma unroll
    for (int i2 = 0; i2 < 8; ++i2) {
        const float h0 = hl[i2].x;
        const float h1 = hl[i2].y;
        const float4* w0 = reinterpret_cast<const float4*>(&sW0t[(2 * i2) * 16]);
        const float4* w1 = reinterpret_cast<const float4*>(&sW0t[(2 * i2 + 1) * 16]);
        #pragma unroll
        for (int q = 0; q < 4; ++q) {
            const float4 wa = w0[q];
            const float4 wb = w1[q];
            a[2 * q]     += h0 * (v2f){wa.x, wa.y};
            a[2 * q + 1] += h0 * (v2f){wa.z, wa.w};
            a[2 * q]     += h1 * (v2f){wb.x, wb.y};
            a[2 * q + 1] += h1 * (v2f){wb.z, wb.w};
        }
    }
    const v2f zz = {0.0f, 0.0f};
    v2f h1v[8];
    #pragma unroll
    for (int j = 0; j < 8; ++j) h1v[j] = __builtin_elementwise_max(a[j], zz);

    #pragma unroll
    for (int j = 0; j < 8; ++j) a[j] = (v2f){0.0f, 0.0f};
    #pragma unroll
    for (int i2 = 0; i2 < 8; ++i2) {
        const float h0 = h1v[i2].x;
        const float h1 = h1v[i2].y;
        const float4* w0 = reinterpret_cast<const float4*>(&sW1t[(2 * i2) * 16]);
        const float4* w1 = reinterpret_cast<const float4*>(&sW1t[(2 * i2 + 1) * 16]);
        #pragma unroll
        for (int q = 0; q < 4; ++q) {
            const float4 wa = w0[q];
            const float4 wb = w1[q];
            a[2 * q]     += h0 * (v2f){wa.x, wa.y};
            a[2 * q + 1] += h0 * (v2f){wa.z, wa.w};
            a[2 * q]     += h1 * (v2f){wb.x, wb.y};
            a[2 * q + 1] += h1 * (v2f){wb.z, wb.w};
        }
    }

    v2f acco = {0.0f, 0.0f};
    #pragma unroll
    for (int j = 0; j < 8; ++j) {
        const v2f h2 = __builtin_elementwise_max(a[j], zz);
        acco += h2 * (v2f){sW2[2 * j], sW2[2 * j + 1]};
    }
    out[gid] = acco.x + acco.y;
}

extern "C" void kernel_launch(void* const* d_in, const int* in_sizes, int n_in,
                              void* d_out, int out_size, void* d_ws, size_t ws_size,
                              hipStream_t stream) {
    const float* x     = (const float*)d_in[0];
    const float* table = (const float*)d_in[1];
    const float* W0    = (const float*)d_in[2];
    const float* W1    = (const float*)d_in[3];
    const float* W2    = (const float*)d_in[4];
    float* out = (float*)d_out;

    const int N = in_sizes[0] / 3;

    EncParams ep;
    const double g = pow(4.0, 1.0 / 7.0);
    for (int l = 0; l < 8; ++l) {
        ep.scale[l] = (float)(8.0 * pow(g, (double)l) - 1.0);
    }

    const size_t cellBytes = (size_t)TOTCELLS * 64;

    if (ws_size >= cellBytes) {
        float4* cells = (float4*)d_ws;
        hipLaunchKernelGGL(build_cells, dim3((TOTCELLS + 255) / 256), dim3(256),
                           0, stream, table, cells);
        const int blocks = (N + 255) / 256;
        hipLaunchKernelGGL(sdf_cell_kernel, dim3(blocks), dim3(256), 0, stream,
                           x, cells, W0, W1, W2, out, N, ep);
    } else {
        const int blocks = (N + 255) / 256;
        hipLaunchKernelGGL(sdf_fused_fallback, dim3(blocks), dim3(256), 0, stream,
                           x, table, W0, W1, W2, out, N, ep);
    }
}

// Round 5
// 159.429 us; speedup vs baseline: 3.7382x; 1.8854x over previous
//
#include <hip/hip_runtime.h>
#include <math.h>

// Round 5: fp16 compaction + LDS coarse levels + deep load ILP.
// Round 4 post-mortem: f32 cell array (4.8MB) > per-XCD 4MB L2 alongside the
// 48MB x stream -> 140MB L2-miss traffic at 500GB/s, latency-bound
// (VALUBusy 23%); VGPR=40 shows the compiler serialized gathers.
// Fixes:
//  - levels 3..7: fp16 cells, 32B each (2.3MB, L2-resident); one line/point/level
//  - levels 0..2: fp16 rows (17KB) staged in LDS per block -> off the L1 path
//  - all 10 cell loads issued up-front into live arrays (ILP), lb(256,4)
//  - nontemporal x loads / out stores so streams don't evict cells from L2
// Interp + MLP stay fp32 (fp16 storage err ~1e-7 << 2.3e-6 threshold).

typedef float v2f __attribute__((ext_vector_type(2)));

struct EncParams { float scale[8]; };

__constant__ constexpr int SIDE[8]   = {9, 11, 13, 16, 19, 23, 28, 33};
__constant__ constexpr int ROWOFF[8] = {0, 729, 2060, 4257, 8353, 15212, 27379, 49331};
__constant__ constexpr int CS[8]     = {8, 10, 12, 15, 18, 22, 27, 32};
// cell-array bases for levels 3..7 (rebased to 0 at level 3)
__constant__ constexpr int CBH[8]    = {0, 0, 0, 0, 3375, 9207, 19855, 39538};
#define NROWS_H  4257    // rows of levels 0..2
#define NCELLS_H 72306   // cells of levels 3..7

__device__ __forceinline__ unsigned int pack2h(float a, float b) {
    _Float16 ha = (_Float16)a, hb = (_Float16)b;
    unsigned short ua = __builtin_bit_cast(unsigned short, ha);
    unsigned short ub = __builtin_bit_cast(unsigned short, hb);
    return (unsigned int)ua | ((unsigned int)ub << 16);
}
__device__ __forceinline__ float2 unpack2h(unsigned int u) {
    _Float16 ha = __builtin_bit_cast(_Float16, (unsigned short)(u & 0xffffu));
    _Float16 hb = __builtin_bit_cast(_Float16, (unsigned short)(u >> 16));
    return make_float2((float)ha, (float)hb);
}

// ---- build fp16 row copy of levels 0..2 ----
__global__ __launch_bounds__(256) void build_rows_h(
    const float* __restrict__ table, unsigned int* __restrict__ rowsH)
{
    const int i = blockIdx.x * 256 + threadIdx.x;
    if (i >= NROWS_H) return;
    rowsH[i] = pack2h(table[2 * i], table[2 * i + 1]);
}

// ---- build fp16 per-cell 32B corner blocks for levels 3..7 ----
// cell c: 2x uint4.  qa = {q0.lo,q0.hi,q1.lo,q1.hi}, qb = {q2.lo,q2.hi,q3.lo,q3.hi}
// quadrant q = dz*2+dy; lo = {h(x0.f0),h(x0.f1)}, hi = {h(x1.f0),h(x1.f1)}
__global__ __launch_bounds__(256) void build_cells_h(
    const float* __restrict__ table, uint4* __restrict__ cellsH)
{
    const int c = blockIdx.x * 256 + threadIdx.x;
    if (c >= NCELLS_H) return;

    int l = 3;
    #pragma unroll
    for (int i = 4; i < 8; ++i) if (c >= CBH[i]) l = i;

    const int cs  = CS[l];
    const int rem = c - CBH[l];
    const int ix  = rem % cs;
    const int t1  = rem / cs;
    const int iy  = t1 % cs;
    const int iz  = t1 / cs;

    const int side  = SIDE[l];
    const int side2 = side * side;
    const int row   = ROWOFF[l] + ix + iy * side + iz * side2;

    unsigned int q[8];
    #pragma unroll
    for (int dz = 0; dz < 2; ++dz) {
        #pragma unroll
        for (int dy = 0; dy < 2; ++dy) {
            const int r = row + dy * side + dz * side2;
            q[(dz * 2 + dy) * 2 + 0] = pack2h(table[2 * r + 0], table[2 * r + 1]);
            q[(dz * 2 + dy) * 2 + 1] = pack2h(table[2 * r + 2], table[2 * r + 3]);
        }
    }
    cellsH[2 * c + 0] = make_uint4(q[0], q[1], q[2], q[3]);
    cellsH[2 * c + 1] = make_uint4(q[4], q[5], q[6], q[7]);
}

__device__ __forceinline__ void interp_quad(
    v2f& acc, unsigned int lo, unsigned int hi, float wyz, float wx0, float rx)
{
    const float2 f0 = unpack2h(lo);
    const float2 f1 = unpack2h(hi);
    acc += (wyz * wx0) * (v2f){f0.x, f0.y} + (wyz * rx) * (v2f){f1.x, f1.y};
}

// ---- main fused kernel ----
__global__ __launch_bounds__(256, 4) void sdf_main(
    const float* __restrict__ x,
    const unsigned int* __restrict__ rowsH,
    const uint4* __restrict__ cellsH,
    const float* __restrict__ W0,
    const float* __restrict__ W1,
    const float* __restrict__ W2,
    float* __restrict__ out,
    int N, EncParams ep)
{
    __shared__ unsigned int sRows[NROWS_H];      // 17,028 B
    __shared__ __align__(16) float sW0t[256];    // transposed [i][j]
    __shared__ __align__(16) float sW1t[256];
    __shared__ __align__(16) float sW2[16];

    const int t = threadIdx.x;
    const int gid = blockIdx.x * 256 + t;

    float px = 0.f, py = 0.f, pz = 0.f;
    if (gid < N) {
        px = __builtin_nontemporal_load(x + 3 * gid + 0);
        py = __builtin_nontemporal_load(x + 3 * gid + 1);
        pz = __builtin_nontemporal_load(x + 3 * gid + 2);
    }

    sW0t[(t & 15) * 16 + (t >> 4)] = W0[t];
    sW1t[(t & 15) * 16 + (t >> 4)] = W1[t];
    if (t < 16) sW2[t] = W2[t];
    for (int i = t; i < NROWS_H; i += 256) sRows[i] = rowsH[i];
    __syncthreads();

    if (gid >= N) return;

    // ---- phase A: all fracs + addresses; issue all global cell loads ----
    float frx[8], fry[8], frz[8];
    int rbase[3];
    int cidx[5];
    #pragma unroll
    for (int l = 0; l < 8; ++l) {
        const float s = ep.scale[l];
        const float fx = px * s + 0.5f;
        const float fy = py * s + 0.5f;
        const float fz = pz * s + 0.5f;
        const float gx = floorf(fx), gy = floorf(fy), gz = floorf(fz);
        frx[l] = fx - gx; fry[l] = fy - gy; frz[l] = fz - gz;
        const int ix = (int)gx, iy = (int)gy, iz = (int)gz;
        if (l < 3) {
            rbase[l] = ROWOFF[l] + ix + iy * SIDE[l] + iz * SIDE[l] * SIDE[l];
        } else {
            cidx[l - 3] = CBH[l] + (iz * CS[l] + iy) * CS[l] + ix;
        }
    }

    uint4 qa[5], qb[5];
    #pragma unroll
    for (int k = 0; k < 5; ++k) {
        const uint4* cp = cellsH + 2 * cidx[k];
        qa[k] = cp[0];
        qb[k] = cp[1];
    }

    v2f hl[8];

    // ---- levels 0..2 from LDS (overlaps global loads) ----
    #pragma unroll
    for (int l = 0; l < 3; ++l) {
        const int side = SIDE[l], side2 = side * side;
        const float rx = frx[l], ry = fry[l], rz = frz[l];
        const float wx0 = 1.0f - rx, wy0 = 1.0f - ry, wz0 = 1.0f - rz;
        v2f acc = {0.0f, 0.0f};
        #pragma unroll
        for (int dz = 0; dz < 2; ++dz) {
            const float wz = dz ? rz : wz0;
            #pragma unroll
            for (int dy = 0; dy < 2; ++dy) {
                const float wyz = (dy ? ry : wy0) * wz;
                const int r = rbase[l] + dy * side + dz * side2;
                const unsigned int u0 = sRows[r];
                const unsigned int u1 = sRows[r + 1];
                const float2 f0 = unpack2h(u0);
                const float2 f1 = unpack2h(u1);
                acc += (wyz * wx0) * (v2f){f0.x, f0.y}
                     + (wyz * rx)  * (v2f){f1.x, f1.y};
            }
        }
        hl[l] = acc;
    }

    // ---- levels 3..7 from the fp16 cell array ----
    #pragma unroll
    for (int k = 0; k < 5; ++k) {
        const int l = k + 3;
        const float rx = frx[l], ry = fry[l], rz = frz[l];
        const float wx0 = 1.0f - rx, wy0 = 1.0f - ry, wz0 = 1.0f - rz;
        v2f acc = {0.0f, 0.0f};
        interp_quad(acc, qa[k].x, qa[k].y, wy0 * wz0, wx0, rx);
        interp_quad(acc, qa[k].z, qa[k].w, ry  * wz0, wx0, rx);
        interp_quad(acc, qb[k].x, qb[k].y, wy0 * rz,  wx0, rx);
        interp_quad(acc, qb[k].z, qb[k].w, ry  * rz,  wx0, rx);
        hl[l] = acc;
    }

    // ---- MLP, packed fp32 ----
    v2f a[8];
    #pragma unroll
    for (int j = 0; j < 8; ++j) a[j] = (v2f){0.0f, 0.0f};
    #pragma unroll
    for (int i2 = 0; i2 < 8; ++i2) {
        const float h0 = hl[i2].x;
        const float h1 = hl[i2].y;
        const float4* w0 = reinterpret_cast<const float4*>(&sW0t[(2 * i2) * 16]);
        const float4* w1 = reinterpret_cast<const float4*>(&sW0t[(2 * i2 + 1) * 16]);
        #pragma unroll
        for (int q = 0; q < 4; ++q) {
            const float4 wa = w0[q];
            const float4 wb = w1[q];
            a[2 * q]     += h0 * (v2f){wa.x, wa.y};
            a[2 * q + 1] += h0 * (v2f){wa.z, wa.w};
            a[2 * q]     += h1 * (v2f){wb.x, wb.y};
            a[2 * q + 1] += h1 * (v2f){wb.z, wb.w};
        }
    }
    const v2f zz = {0.0f, 0.0f};
    v2f h1v[8];
    #pragma unroll
    for (int j = 0; j < 8; ++j) h1v[j] = __builtin_elementwise_max(a[j], zz);

    #pragma unroll
    for (int j = 0; j < 8; ++j) a[j] = (v2f){0.0f, 0.0f};
    #pragma unroll
    for (int i2 = 0; i2 < 8; ++i2) {
        const float h0 = h1v[i2].x;
        const float h1 = h1v[i2].y;
        const float4* w0 = reinterpret_cast<const float4*>(&sW1t[(2 * i2) * 16]);
        const float4* w1 = reinterpret_cast<const float4*>(&sW1t[(2 * i2 + 1) * 16]);
        #pragma unroll
        for (int q = 0; q < 4; ++q) {
            const float4 wa = w0[q];
            const float4 wb = w1[q];
            a[2 * q]     += h0 * (v2f){wa.x, wa.y};
            a[2 * q + 1] += h0 * (v2f){wa.z, wa.w};
            a[2 * q]     += h1 * (v2f){wb.x, wb.y};
            a[2 * q + 1] += h1 * (v2f){wb.z, wb.w};
        }
    }

    v2f acco = {0.0f, 0.0f};
    #pragma unroll
    for (int j = 0; j < 8; ++j) {
        const v2f h2 = __builtin_elementwise_max(a[j], zz);
        acco += h2 * (v2f){sW2[2 * j], sW2[2 * j + 1]};
    }
    __builtin_nontemporal_store(acco.x + acco.y, out + gid);
}

// ---- fallback: direct f32 row-major gather, if ws too small ----
__global__ __launch_bounds__(256) void sdf_fused_fallback(
    const float* __restrict__ x,
    const float* __restrict__ table,
    const float* __restrict__ W0,
    const float* __restrict__ W1,
    const float* __restrict__ W2,
    float* __restrict__ out,
    int N, EncParams ep)
{
    __shared__ __align__(16) float sW0t[256];
    __shared__ __align__(16) float sW1t[256];
    __shared__ __align__(16) float sW2[16];

    const int t = threadIdx.x;
    sW0t[(t & 15) * 16 + (t >> 4)] = W0[t];
    sW1t[(t & 15) * 16 + (t >> 4)] = W1[t];
    if (t < 16) sW2[t] = W2[t];
    __syncthreads();

    const int gid = blockIdx.x * 256 + t;
    if (gid >= N) return;

    const float px = x[3 * gid + 0];
    const float py = x[3 * gid + 1];
    const float pz = x[3 * gid + 2];

    v2f hl[8];
    #pragma unroll
    for (int l = 0; l < 8; ++l) {
        const int side  = SIDE[l];
        const int side2 = side * side;
        const float s = ep.scale[l];
        const float fx = px * s + 0.5f;
        const float fy = py * s + 0.5f;
        const float fz = pz * s + 0.5f;
        const float gx = floorf(fx), gy = floorf(fy), gz = floorf(fz);
        const float rx = fx - gx, ry = fy - gy, rz = fz - gz;
        const int ix = (int)gx, iy = (int)gy, iz = (int)gz;
        const int base = ROWOFF[l] + ix + iy * side + iz * side2;
        const float wx0 = 1.0f - rx, wy0 = 1.0f - ry, wz0 = 1.0f - rz;

        v2f acc = {0.0f, 0.0f};
        #pragma unroll
        for (int dz = 0; dz < 2; ++dz) {
            const float wz = dz ? rz : wz0;
            #pragma unroll
            for (int dy = 0; dy < 2; ++dy) {
                const float wyz = (dy ? ry : wy0) * wz;
                const int r = base + dy * side + dz * side2;
                const float4 f = *reinterpret_cast<const float4*>(table + 2 * r);
                acc += (wyz * wx0) * (v2f){f.x, f.y}
                     + (wyz * rx)  * (v2f){f.z, f.w};
            }
        }
        hl[l] = acc;
    }

    v2f a[8];
    #pragma unroll
    for (int j = 0; j < 8; ++j) a[j] = (v2f){0.0f, 0.0f};
    #pragma unroll
    for (int i2 = 0; i2 < 8; ++i2) {
        const float h0 = hl[i2].x;
        const float h1 = hl[i2].y;
        const float4* w0 = reinterpret_cast<const float4*>(&sW0t[(2 * i2) * 16]);
        const float4* w1 = reinterpret_cast<const float4*>(&sW0t[(2 * i2 + 1) * 16]);
        #pragma unroll
        for (int q = 0; q < 4; ++q) {
            const float4 wa = w0[q];
            const float4 wb = w1[q];
            a[2 * q]     += h0 * (v2f){wa.x, wa.y};
            a[2 * q + 1] += h0 * (v2f){wa.z, wa.w};
            a[2 * q]     += h1 * (v2f){wb.x, wb.y};
            a[2 * q + 1] += h1 * (v2f){wb.z, wb.w};
        }
    }
    const v2f zz = {0.0f, 0.0f};
    v2f h1v[8];
    #pragma unroll
    for (int j = 0; j < 8; ++j) h1v[j] = __builtin_elementwise_max(a[j], zz);

    #pragma unroll
    for (int j = 0; j < 8; ++j) a[j] = (v2f){0.0f, 0.0f};
    #pragma unroll
    for (int i2 = 0; i2 < 8; ++i2) {
        const float h0 = h1v[i2].x;
        const float h1 = h1v[i2].y;
        const float4* w0 = reinterpret_cast<const float4*>(&sW1t[(2 * i2) * 16]);
        const float4* w1 = reinterpret_cast<const float4*>(&sW1t[(2 * i2 + 1) * 16]);
        #pragma unroll
        for (int q = 0; q < 4; ++q) {
            const float4 wa = w0[q];
            const float4 wb = w1[q];
            a[2 * q]     += h0 * (v2f){wa.x, wa.y};
            a[2 * q + 1] += h0 * (v2f){wa.z, wa.w};
            a[2 * q]     += h1 * (v2f){wb.x, wb.y};
            a[2 * q + 1] += h1 * (v2f){wb.z, wb.w};
        }
    }

    v2f acco = {0.0f, 0.0f};
    #pragma unroll
    for (int j = 0; j < 8; ++j) {
        const v2f h2 = __builtin_elementwise_max(a[j], zz);
        acco += h2 * (v2f){sW2[2 * j], sW2[2 * j + 1]};
    }
    out[gid] = acco.x + acco.y;
}

extern "C" void kernel_launch(void* const* d_in, const int* in_sizes, int n_in,
                              void* d_out, int out_size, void* d_ws, size_t ws_size,
                              hipStream_t stream) {
    const float* x     = (const float*)d_in[0];
    const float* table = (const float*)d_in[1];
    const float* W0    = (const float*)d_in[2];
    const float* W1    = (const float*)d_in[3];
    const float* W2    = (const float*)d_in[4];
    float* out = (float*)d_out;

    const int N = in_sizes[0] / 3;

    EncParams ep;
    const double g = pow(4.0, 1.0 / 7.0);
    for (int l = 0; l < 8; ++l) {
        ep.scale[l] = (float)(8.0 * pow(g, (double)l) - 1.0);
    }

    const size_t cellsOff = 17408;                       // rows (17,028B) + pad
    const size_t needBytes = cellsOff + (size_t)NCELLS_H * 32;

    const int blocks = (N + 255) / 256;
    if (ws_size >= needBytes) {
        unsigned int* rowsH = (unsigned int*)d_ws;
        uint4* cellsH = (uint4*)((char*)d_ws + cellsOff);
        hipLaunchKernelGGL(build_rows_h, dim3((NROWS_H + 255) / 256), dim3(256),
                           0, stream, table, rowsH);
        hipLaunchKernelGGL(build_cells_h, dim3((NCELLS_H + 255) / 256), dim3(256),
                           0, stream, table, cellsH);
        hipLaunchKernelGGL(sdf_main, dim3(blocks), dim3(256), 0, stream,
                           x, rowsH, cellsH, W0, W1, W2, out, N, ep);
    } else {
        hipLaunchKernelGGL(sdf_fused_fallback, dim3(blocks), dim3(256), 0, stream,
                           x, table, W0, W1, W2, out, N, ep);
    }
}